// Round 15
// baseline (408.903 us; speedup 1.0000x reference)
//
#include <hip/hip_runtime.h>
#include <hip/hip_bf16.h>

// GAE forward, bf16 compute path + fp8 message tensor.
//   CSR build: 8-way privatized count (saves per-edge RANK + packed (s,d) pair)
//     -> 3-phase scan (+per-copy base8) -> ATOMIC-FREE scatter (fused w/ W-pack)
//   -> 5x bf16-MFMA GEMM (K compile-time; GEMM1 converts f32 x in-register)
//   -> 3x COLUMN-CHUNKED mp gather (r15: 4 chunks of 64 cols -> 3.2MB slice fits
//      per-XCD 4MB L2 -> gathers become L2 hits instead of L3-latency;
//      16 nodes x 16 lanes per block, 1 dword/lane, grid ordered chunk-major)
//   -> ATOMIC-FREE pool partials -> head (1024 thr; folds partial reduce)
//   -> fill(sigmoid const)
// Lessons: r8 pool atomics ping-pong; r9 head serial-load chain; r10 scatter
// atomic serialization; r12 conv GEMM access-pattern limited; r13 dispatch gaps.
// edge_probs is constant: node_emb rows are the same broadcast vector v,
// so logit = sum(v*v) for every edge.

typedef __attribute__((ext_vector_type(8))) short bf16x8;
typedef __attribute__((ext_vector_type(4))) float f32x4;
typedef __attribute__((ext_vector_type(2))) float f32x2;

#define FP8_SCALE 32.0f
#define FP8_INV (1.0f / 32.0f)

__device__ __forceinline__ ushort f2bf(float f) {
  union { float f; unsigned u; } v; v.f = f;
  unsigned r = v.u + 0x7FFF + ((v.u >> 16) & 1);  // RNE
  return (ushort)(r >> 16);
}
__device__ __forceinline__ float bf2f(ushort b) {
  union { unsigned u; float f; } v; v.u = ((unsigned)b) << 16;
  return v.f;
}

// -------------------- CSR build --------------------

// fused: zero cnt8 + detect edge dtype (block 0 thread 0)
__global__ void init_detect_kernel(const int* __restrict__ ei, int* __restrict__ flag,
                                   int* __restrict__ cnt8, int N8) {
  int i = blockIdx.x * 256 + threadIdx.x;
  if (i < N8) cnt8[i] = 0;
  if (blockIdx.x == 0 && threadIdx.x == 0) {
    int all0 = 1;
    for (int k = 0; k < 128; ++k) {
      if (ei[2 * k + 1] != 0) { all0 = 0; break; }
    }
    flag[0] = all0;  // 1 => int64 payload (high words all zero)
  }
}

// 8-way privatized histogram; the atomic's return value IS the edge's rank
// within copy (blockIdx&7). Also emits packed (s,d) pair so scatter never
// re-reads the (possibly int64) edge list.
__global__ void count_kernel(const int* __restrict__ ei, const int* __restrict__ flag,
                             int* __restrict__ cnt8, int* __restrict__ rank,
                             unsigned* __restrict__ pairs, int E, int N) {
  int e = blockIdx.x * 256 + threadIdx.x;
  if (e >= E) return;
  int s, d;
  if (flag[0]) {
    const long long* e64 = (const long long*)ei;
    s = (int)e64[e];
    d = (int)e64[(size_t)E + e];
  } else {
    s = ei[e];
    d = ei[(size_t)E + e];
  }
  rank[e] = atomicAdd(&cnt8[(size_t)(blockIdx.x & 7) * N + d], 1);
  pairs[e] = (unsigned)s | ((unsigned)d << 16);  // s,d < 65536
}

// 3-phase multiblock exclusive scan -> rowptr[N+1], per-copy base8, dinv.
// bsum fuses the 8-copy histogram reduce (writes cnt[i] = total).

__global__ __launch_bounds__(256) void bsum_kernel(const int* __restrict__ cnt8,
                                                   int* __restrict__ cnt,
                                                   int* __restrict__ bsum, int N) {
  __shared__ int red[4];
  int t = threadIdx.x;
  int i = blockIdx.x * 256 + t;
  int v = 0;
  if (i < N) {
#pragma unroll
    for (int c = 0; c < 8; ++c) v += cnt8[(size_t)c * N + i];
    cnt[i] = v;
  }
  for (int off = 32; off > 0; off >>= 1) v += __shfl_down(v, off, 64);
  if ((t & 63) == 0) red[t >> 6] = v;
  __syncthreads();
  if (t == 0) bsum[blockIdx.x] = red[0] + red[1] + red[2] + red[3];
}

__global__ __launch_bounds__(256) void bscan_kernel(const int* __restrict__ bsum,
                                                    int* __restrict__ boff,
                                                    int* __restrict__ rowptr, int B, int N) {
  __shared__ int s[256];
  int t = threadIdx.x;
  int v = (t < B) ? bsum[t] : 0;
  s[t] = v;
  __syncthreads();
  for (int off = 1; off < 256; off <<= 1) {
    int x = s[t];
    int add = (t >= off) ? s[t - off] : 0;
    __syncthreads();
    s[t] = x + add;
    __syncthreads();
  }
  if (t < B) boff[t] = s[t] - v;  // exclusive block offset
  if (t == 255) rowptr[N] = s[255];
}

__global__ __launch_bounds__(256) void rowptr_kernel(const int* __restrict__ cnt,
                                                     const int* __restrict__ cnt8,
                                                     const int* __restrict__ boff,
                                                     int* __restrict__ rowptr,
                                                     int* __restrict__ base8,
                                                     float* __restrict__ dinv, int N) {
  __shared__ int s[256];
  int t = threadIdx.x;
  int i = blockIdx.x * 256 + t;
  int v = (i < N) ? cnt[i] : 0;
  s[t] = v;
  __syncthreads();
  for (int off = 1; off < 256; off <<= 1) {
    int x = s[t];
    int add = (t >= off) ? s[t - off] : 0;
    __syncthreads();
    s[t] = x + add;
    __syncthreads();
  }
  if (i < N) {
    int rp = boff[blockIdx.x] + s[t] - v;
    rowptr[i] = rp;
    int run = rp;
#pragma unroll
    for (int c = 0; c < 8; ++c) {            // per-copy exclusive base within the row
      base8[(size_t)c * N + i] = run;
      run += cnt8[(size_t)c * N + i];
    }
    dinv[i] = rsqrtf((float)(v + 1));  // +1 self-loop
  }
}

// ---- fused: ATOMIC-FREE scatter + weight-frag packing (independent work) ----
// Scatter: slot = base8[copy][d] + rank[e]; copy = (e>>8)&7 matches count's
// blockIdx&7 (identical 256-thr grids).
// Wp layout: [K/32][16 colblk][64 lane][8 bf16], element (ks,cb,lane,i):
//   k = ks*32 + (lane>>4)*8 + i,  n = cb*16 + (lane&15)   (MFMA B-frag order)

__global__ void scatter_pack_kernel(const unsigned* __restrict__ pairs,
                                    const int* __restrict__ rank,
                                    const int* __restrict__ base8,
                                    ushort* __restrict__ col, int E, int N, int nScat,
                                    const float* __restrict__ W1, ushort* __restrict__ Wp1,
                                    const float* __restrict__ W2, ushort* __restrict__ Wp2,
                                    const float* __restrict__ cW, ushort* __restrict__ Wpc) {
  int b = blockIdx.x;
  if (b < nScat) {
    int e = b * 256 + threadIdx.x;
    if (e >= E) return;
    unsigned p = pairs[e];
    int s = p & 0xffff;
    int d = p >> 16;
    int c = (e >> 8) & 7;
    int pos = base8[(size_t)c * N + d] + rank[e];
    col[pos] = (ushort)s;
    return;
  }
  b -= nScat;
  const float* W;
  ushort* Wp;
  int K;
  if (b < 8) { W = W1; Wp = Wp1; K = 64; }
  else if (b < 40) { W = W2; Wp = Wp2; K = 256; b -= 8; }
  else {
    int l = (b - 40) >> 5;
    W = cW + (size_t)l * 256 * 256;
    Wp = Wpc + (size_t)l * 8 * 16 * 64 * 8;
    K = 256;
    b -= 40 + l * 32;
  }
  int idx = b * 256 + threadIdx.x;
  int total = (K >> 5) * 16 * 64;
  if (idx >= total) return;
  int lane = idx & 63;
  int cb = (idx >> 6) & 15;
  int ks = idx >> 10;
  int nn = cb * 16 + (lane & 15);
  int kbase = ks * 32 + (lane >> 4) * 8;
#pragma unroll
  for (int i = 0; i < 8; ++i)
    Wp[(size_t)idx * 8 + i] = f2bf(W[(size_t)(kbase + i) * 256 + nn]);
}

// -------------------- bf16 MFMA GEMM: C[M,256] = post(A[M,K*] @ W) ------------------
// K compile-time (NKS = K/32); block = 256 thr (4 waves), tile 64x256.
// AF32: A is f32 row-major, converted to bf16 in-register (saves the cvt pass).

template <int NKS, bool AF32>
__global__ __launch_bounds__(256) void gemm_mfma_kernel(
    const void* __restrict__ Av,    // [Mpad,K] bf16 (or [M,K] f32 if AF32)
    const ushort* __restrict__ Wp,  // packed frags
    const float* __restrict__ bias, // [256] or null
    const float* __restrict__ scale,// [M] dinv or null (applied after bias/relu)
    ushort* __restrict__ C,         // [Mpad,256] bf16 (if C8 == null)
    unsigned char* __restrict__ C8, // [Mpad,256] fp8 (or null)
    int M, int relu) {
  constexpr int K = NKS * 32;
  int t = threadIdx.x;
  int lane = t & 63, wave = t >> 6;
  int l15 = lane & 15, lk = lane >> 4;
  int row0 = blockIdx.x * 64;

  f32x4 acc[4][4];
#pragma unroll
  for (int rb = 0; rb < 4; ++rb)
#pragma unroll
    for (int cb = 0; cb < 4; ++cb) acc[rb][cb] = (f32x4){0.f, 0.f, 0.f, 0.f};

  const ushort* abase[4];
  const float* afbase[4];
#pragma unroll
  for (int rb = 0; rb < 4; ++rb) {
    int arow = row0 + rb * 16 + l15;
    if (AF32) arow = min(arow, M - 1);  // clamp: keep loads in-bounds (stores guarded)
    if (AF32) afbase[rb] = (const float*)Av + (size_t)arow * K + lk * 8;
    else      abase[rb] = (const ushort*)Av + (size_t)arow * K + lk * 8;
  }
  const ushort* bbase = Wp + ((size_t)(wave * 4) * 64 + lane) * 8;

#pragma unroll
  for (int ks = 0; ks < NKS; ++ks) {
    bf16x8 a[4], b[4];
#pragma unroll
    for (int rb = 0; rb < 4; ++rb) {
      if (AF32) {
        float4 f0 = *reinterpret_cast<const float4*>(afbase[rb] + ks * 32);
        float4 f1 = *reinterpret_cast<const float4*>(afbase[rb] + ks * 32 + 4);
        bf16x8 av;
        av[0] = (short)f2bf(f0.x); av[1] = (short)f2bf(f0.y);
        av[2] = (short)f2bf(f0.z); av[3] = (short)f2bf(f0.w);
        av[4] = (short)f2bf(f1.x); av[5] = (short)f2bf(f1.y);
        av[6] = (short)f2bf(f1.z); av[7] = (short)f2bf(f1.w);
        a[rb] = av;
      } else {
        a[rb] = *reinterpret_cast<const bf16x8*>(abase[rb] + ks * 32);
      }
    }
#pragma unroll
    for (int cb = 0; cb < 4; ++cb)
      b[cb] = *reinterpret_cast<const bf16x8*>(bbase + ((size_t)ks * 16 + cb) * 64 * 8);
#pragma unroll
    for (int rb = 0; rb < 4; ++rb)
#pragma unroll
      for (int cb = 0; cb < 4; ++cb)
        acc[rb][cb] = __builtin_amdgcn_mfma_f32_16x16x32_bf16(a[rb], b[cb], acc[rb][cb], 0, 0, 0);
  }

  float bv[4];
#pragma unroll
  for (int cb = 0; cb < 4; ++cb)
    bv[cb] = bias ? bias[wave * 64 + cb * 16 + l15] : 0.f;

#pragma unroll
  for (int rb = 0; rb < 4; ++rb) {
    int rbase = row0 + rb * 16 + lk * 4;
#pragma unroll
    for (int r = 0; r < 4; ++r) {
      int row = rbase + r;
      if (row >= M) continue;
      float sc = scale ? scale[row] : 1.f;
#pragma unroll
      for (int cb = 0; cb < 4; ++cb) {
        float v = acc[rb][cb][r] + bv[cb];
        if (relu) v = fmaxf(v, 0.f);
        v *= sc;
        int colIdx = wave * 64 + cb * 16 + l15;
        if (C8) {
          float vq = fminf(fmaxf(v * FP8_SCALE, -448.f), 448.f);
          unsigned p = __builtin_amdgcn_cvt_pk_fp8_f32(vq, vq, 0, false);
          C8[(size_t)row * 256 + colIdx] = (unsigned char)(p & 0xff);
        } else {
          C[(size_t)row * 256 + colIdx] = f2bf(v);
        }
      }
    }
  }
}

// -------- message passing, COLUMN-CHUNKED --------
// h[n] = relu(dinv[n]*(sum_{s in in(n)} hw'[s] + hw'[n]) + b); hw' is fp8 e4m3
// of (hw * dinv[src] * FP8_SCALE). Chunk c covers cols [c*64, c*64+64): the
// active slice of hw8 is 3.2MB -> per-XCD-L2 resident, gathers become L2 hits.
// Block = 256 thr = 16 nodes x 16 lanes; lane owns 1 dword (4 fp8 cols); a
// node-group's 16 lanes read one contiguous 64B line per edge. Grid is
// chunk-major so concurrently-resident blocks share one chunk's slice.

__global__ __launch_bounds__(256) void mp_chunk_kernel(const unsigned char* __restrict__ hw8,
                                                       const int* __restrict__ rowptr,
                                                       const ushort* __restrict__ col,
                                                       const float* __restrict__ dinv,
                                                       const float* __restrict__ bias,
                                                       ushort* __restrict__ hout,
                                                       int N, int bpc) {
  int chunk = blockIdx.x / bpc;
  int nb = blockIdx.x - chunk * bpc;
  int t = threadIdx.x;
  int g = t >> 4;          // node group 0..15
  int l = t & 15;          // lane within group
  int n = nb * 16 + g;
  if (n >= N) return;
  int cd = chunk * 16 + l;  // dword column index in [0,64)
  const unsigned* hw32 = reinterpret_cast<const unsigned*>(hw8);

  unsigned ws = hw32[(size_t)n * 64 + cd];  // self
  f32x2 lo = __builtin_amdgcn_cvt_pk_f32_fp8(ws, false);
  f32x2 hi = __builtin_amdgcn_cvt_pk_f32_fp8(ws, true);
  float ax = lo[0], ay = lo[1], az = hi[0], aw = hi[1];

  int beg = rowptr[n], end = rowptr[n + 1];
  int j = beg;
  for (; j + 8 <= end; j += 8) {
    int ss[8];
    unsigned ww[8];
#pragma unroll
    for (int q = 0; q < 8; ++q) ss[q] = col[j + q];
#pragma unroll
    for (int q = 0; q < 8; ++q) ww[q] = hw32[(size_t)ss[q] * 64 + cd];
#pragma unroll
    for (int q = 0; q < 8; ++q) {
      f32x2 lq = __builtin_amdgcn_cvt_pk_f32_fp8(ww[q], false);
      f32x2 hq = __builtin_amdgcn_cvt_pk_f32_fp8(ww[q], true);
      ax += lq[0]; ay += lq[1]; az += hq[0]; aw += hq[1];
    }
  }
  for (; j < end; ++j) {
    int s = col[j];
    unsigned wv = hw32[(size_t)s * 64 + cd];
    f32x2 l2 = __builtin_amdgcn_cvt_pk_f32_fp8(wv, false);
    f32x2 h2 = __builtin_amdgcn_cvt_pk_f32_fp8(wv, true);
    ax += l2[0]; ay += l2[1]; az += h2[0]; aw += h2[1];
  }
  float dn = dinv[n] * FP8_INV;
  float4 bv = *reinterpret_cast<const float4*>(bias + cd * 4);
  ushort4 o;
  o.x = f2bf(fmaxf(fmaf(dn, ax, bv.x), 0.f));
  o.y = f2bf(fmaxf(fmaf(dn, ay, bv.y), 0.f));
  o.z = f2bf(fmaxf(fmaf(dn, az, bv.z), 0.f));
  o.w = f2bf(fmaxf(fmaf(dn, aw, bv.w), 0.f));
  *reinterpret_cast<ushort4*>(hout + (size_t)n * 256 + cd * 4) = o;
}

// ---------- pooling, ATOMIC-FREE: per-block partials (reduced inside head) ----------

__global__ __launch_bounds__(256) void pool_partial_kernel(const ushort* __restrict__ h,
                                                           float* __restrict__ psum,
                                                           float* __restrict__ pmax, int N) {
  __shared__ float ssum[4][256];
  __shared__ float smax[4][256];
  int t = threadIdx.x;
  int w = t >> 6, l = t & 63;
  int gw = blockIdx.x * 4 + w;  // 0..1023
  float s0 = 0.f, s1 = 0.f, s2 = 0.f, s3 = 0.f;
  float m0 = 0.f, m1 = 0.f, m2 = 0.f, m3 = 0.f;  // h >= 0 after relu
  const ushort4 z = {0, 0, 0, 0};
  for (int r = gw; r < N; r += 8192) {
    ushort4 v[8];
#pragma unroll
    for (int j = 0; j < 8; ++j) {
      int rj = r + j * 1024;
      v[j] = (rj < N) ? *reinterpret_cast<const ushort4*>(h + (size_t)rj * 256 + l * 4) : z;
    }
#pragma unroll
    for (int j = 0; j < 8; ++j) {
      float a0 = bf2f(v[j].x), a1 = bf2f(v[j].y), a2 = bf2f(v[j].z), a3 = bf2f(v[j].w);
      s0 += a0; s1 += a1; s2 += a2; s3 += a3;
      m0 = fmaxf(m0, a0); m1 = fmaxf(m1, a1); m2 = fmaxf(m2, a2); m3 = fmaxf(m3, a3);
    }
  }
  ssum[w][l * 4] = s0; ssum[w][l * 4 + 1] = s1; ssum[w][l * 4 + 2] = s2; ssum[w][l * 4 + 3] = s3;
  smax[w][l * 4] = m0; smax[w][l * 4 + 1] = m1; smax[w][l * 4 + 2] = m2; smax[w][l * 4 + 3] = m3;
  __syncthreads();
  float s = ssum[0][t] + ssum[1][t] + ssum[2][t] + ssum[3][t];
  float m = fmaxf(fmaxf(smax[0][t], smax[1][t]), fmaxf(smax[2][t], smax[3][t]));
  psum[(size_t)blockIdx.x * 256 + t] = s;
  pmax[(size_t)blockIdx.x * 256 + t] = m;
}

// ------- head: folds pool partial-reduce + 4 tiny GEMM layers + logit -------

__global__ __launch_bounds__(1024) void head_kernel(const float* __restrict__ psum,
                                                    const float* __restrict__ pmax,
                                                    const float* __restrict__ Wg1, const float* __restrict__ bg1,
                                                    const float* __restrict__ Wg2, const float* __restrict__ bg2,
                                                    const float* __restrict__ Wd1, const float* __restrict__ bd1,
                                                    const float* __restrict__ Wd2, const float* __restrict__ bd2,
                                                    float* __restrict__ out_ge, float* __restrict__ s_out, int N) {
  __shared__ float gr[512];
  __shared__ float part[4][256];  // also reused flat as [8][128]
  __shared__ float t1[256];
  __shared__ float ge[128];
  __shared__ float t2[256];
  __shared__ float vv[256];
  __shared__ float red[4];
  int t = threadIdx.x;
  float* pf = &part[0][0];

  // fold 256 pool partials: sum
  {
    int kg = t >> 8, c = t & 255;
    const float* base = psum + (size_t)(kg * 64) * 256 + c;
    float a = 0.f;
#pragma unroll
    for (int i = 0; i < 64; i += 4)
      a += (base[(size_t)i * 256] + base[(size_t)(i + 1) * 256]) +
           (base[(size_t)(i + 2) * 256] + base[(size_t)(i + 3) * 256]);
    part[kg][c] = a;
  }
  __syncthreads();
  if (t < 256) gr[t] = (part[0][t] + part[1][t] + part[2][t] + part[3][t]) / (float)N;
  __syncthreads();
  // fold max
  {
    int kg = t >> 8, c = t & 255;
    const float* base = pmax + (size_t)(kg * 64) * 256 + c;
    float m = 0.f;
#pragma unroll
    for (int i = 0; i < 64; i += 4)
      m = fmaxf(m, fmaxf(fmaxf(base[(size_t)i * 256], base[(size_t)(i + 1) * 256]),
                         fmaxf(base[(size_t)(i + 2) * 256], base[(size_t)(i + 3) * 256])));
    part[kg][c] = m;
  }
  __syncthreads();
  if (t < 256)
    gr[256 + t] = fmaxf(fmaxf(part[0][t], part[1][t]), fmaxf(part[2][t], part[3][t]));
  __syncthreads();

  // layer 1: t1 = relu(gr[512] @ Wg1[512,256] + bg1); kg in 0..3 takes 128 k
  {
    int kg = t >> 8, c = t & 255, k0 = kg * 128;
    float a0 = 0, a1 = 0, a2 = 0, a3 = 0, a4 = 0, a5 = 0, a6 = 0, a7 = 0;
    for (int k = k0; k < k0 + 128; k += 8) {
      a0 = fmaf(gr[k + 0], Wg1[(size_t)(k + 0) * 256 + c], a0);
      a1 = fmaf(gr[k + 1], Wg1[(size_t)(k + 1) * 256 + c], a1);
      a2 = fmaf(gr[k + 2], Wg1[(size_t)(k + 2) * 256 + c], a2);
      a3 = fmaf(gr[k + 3], Wg1[(size_t)(k + 3) * 256 + c], a3);
      a4 = fmaf(gr[k + 4], Wg1[(size_t)(k + 4) * 256 + c], a4);
      a5 = fmaf(gr[k + 5], Wg1[(size_t)(k + 5) * 256 + c], a5);
      a6 = fmaf(gr[k + 6], Wg1[(size_t)(k + 6) * 256 + c], a6);
      a7 = fmaf(gr[k + 7], Wg1[(size_t)(k + 7) * 256 + c], a7);
    }
    part[kg][c] = ((a0 + a1) + (a2 + a3)) + ((a4 + a5) + (a6 + a7));
  }
  __syncthreads();
  if (t < 256) t1[t] = fmaxf(part[0][t] + part[1][t] + part[2][t] + part[3][t] + bg1[t], 0.f);
  __syncthreads();

  // layer 2: ge = t1[256] @ Wg2[256,128] + bg2; kg in 0..7 takes 32 k
  {
    int kg = t >> 7, c = t & 127, k0 = kg * 32;
    float a0 = 0, a1 = 0, a2 = 0, a3 = 0;
    for (int k = k0; k < k0 + 32; k += 4) {
      a0 = fmaf(t1[k + 0], Wg2[(size_t)(k + 0) * 128 + c], a0);
      a1 = fmaf(t1[k + 1], Wg2[(size_t)(k + 1) * 128 + c], a1);
      a2 = fmaf(t1[k + 2], Wg2[(size_t)(k + 2) * 128 + c], a2);
      a3 = fmaf(t1[k + 3], Wg2[(size_t)(k + 3) * 128 + c], a3);
    }
    pf[kg * 128 + c] = (a0 + a1) + (a2 + a3);
  }
  __syncthreads();
  if (t < 128) {
    float s = bg2[t];
#pragma unroll
    for (int g = 0; g < 8; ++g) s += pf[g * 128 + t];
    ge[t] = s;
    out_ge[t] = s;  // output 0: graph_embedding
  }
  __syncthreads();

  // layer 3: t2 = relu(ge[128] @ Wd1[128,256] + bd1); kg in 0..3 takes 32 k
  {
    int kg = t >> 8, c = t & 255, k0 = kg * 32;
    float a0 = 0, a1 = 0, a2 = 0, a3 = 0;
    for (int k = k0; k < k0 + 32; k += 4) {
      a0 = fmaf(ge[k + 0], Wd1[(size_t)(k + 0) * 256 + c], a0);
      a1 = fmaf(ge[k + 1], Wd1[(size_t)(k + 1) * 256 + c], a1);
      a2 = fmaf(ge[k + 2], Wd1[(size_t)(k + 2) * 256 + c], a2);
      a3 = fmaf(ge[k + 3], Wd1[(size_t)(k + 3) * 256 + c], a3);
    }
    part[kg][c] = (a0 + a1) + (a2 + a3);
  }
  __syncthreads();
  if (t < 256) t2[t] = fmaxf(part[0][t] + part[1][t] + part[2][t] + part[3][t] + bd1[t], 0.f);
  __syncthreads();

  // layer 4: vv = t2[256] @ Wd2[256,256] + bd2; kg in 0..3 takes 64 k
  {
    int kg = t >> 8, c = t & 255, k0 = kg * 64;
    float a0 = 0, a1 = 0, a2 = 0, a3 = 0, a4 = 0, a5 = 0, a6 = 0, a7 = 0;
    for (int k = k0; k < k0 + 64; k += 8) {
      a0 = fmaf(t2[k + 0], Wd2[(size_t)(k + 0) * 256 + c], a0);
      a1 = fmaf(t2[k + 1], Wd2[(size_t)(k + 1) * 256 + c], a1);
      a2 = fmaf(t2[k + 2], Wd2[(size_t)(k + 2) * 256 + c], a2);
      a3 = fmaf(t2[k + 3], Wd2[(size_t)(k + 3) * 256 + c], a3);
      a4 = fmaf(t2[k + 4], Wd2[(size_t)(k + 4) * 256 + c], a4);
      a5 = fmaf(t2[k + 5], Wd2[(size_t)(k + 5) * 256 + c], a5);
      a6 = fmaf(t2[k + 6], Wd2[(size_t)(k + 6) * 256 + c], a6);
      a7 = fmaf(t2[k + 7], Wd2[(size_t)(k + 7) * 256 + c], a7);
    }
    part[kg][c] = ((a0 + a1) + (a2 + a3)) + ((a4 + a5) + (a6 + a7));
  }
  __syncthreads();
  if (t < 256) vv[t] = part[0][t] + part[1][t] + part[2][t] + part[3][t] + bd2[t];
  __syncthreads();

  // logit = sum(vv^2); sigmoid
  if (t < 256) {
    float p = vv[t] * vv[t];
    for (int off = 32; off > 0; off >>= 1) p += __shfl_down(p, off, 64);
    if ((t & 63) == 0) red[t >> 6] = p;
  }
  __syncthreads();
  if (t == 0) {
    float ssq = red[0] + red[1] + red[2] + red[3];
    s_out[0] = 1.f / (1.f + expf(-ssq));
  }
}

__global__ void fill_kernel(float* __restrict__ out, const float* __restrict__ s_out, int E) {
  int i = (blockIdx.x * 256 + threadIdx.x) * 4;
  if (i + 4 <= E) {
    float s = s_out[0];
    *reinterpret_cast<float4*>(out + i) = make_float4(s, s, s, s);
  } else {
    for (int j = i; j < E; ++j) out[j] = s_out[0];
  }
}

// -------------------- launch --------------------

extern "C" void kernel_launch(void* const* d_in, const int* in_sizes, int n_in,
                              void* d_out, int out_size, void* d_ws, size_t ws_size,
                              hipStream_t stream) {
  const float* x   = (const float*)d_in[0];
  const int*   ei  = (const int*)d_in[1];
  const float* W1  = (const float*)d_in[2];
  const float* b1  = (const float*)d_in[3];
  const float* W2  = (const float*)d_in[4];
  const float* b2  = (const float*)d_in[5];
  const float* cW  = (const float*)d_in[6];
  const float* cb  = (const float*)d_in[7];
  const float* Wg1 = (const float*)d_in[8];
  const float* bg1 = (const float*)d_in[9];
  const float* Wg2 = (const float*)d_in[10];
  const float* bg2 = (const float*)d_in[11];
  const float* Wd1 = (const float*)d_in[12];
  const float* bd1 = (const float*)d_in[13];
  const float* Wd2 = (const float*)d_in[14];
  const float* bd2 = (const float*)d_in[15];
  float* out = (float*)d_out;

  int N = in_sizes[0] / 64;  // 50000
  int E = in_sizes[1] / 2;   // 800000
  int Mpad = (N + 63) & ~63; // 50048
  int B = (N + 255) / 256;   // scan blocks (196)

  size_t off = 0;
  auto walloc = [&](size_t bytes) -> void* {
    void* p = (char*)d_ws + off;
    off += (bytes + 511) & ~(size_t)511;
    return p;
  };
  ushort* hA    = (ushort*)walloc((size_t)Mpad * 256 * 2);
  ushort* hB    = (ushort*)walloc((size_t)Mpad * 256 * 2);
  unsigned char* hA8 = (unsigned char*)walloc((size_t)Mpad * 256);
  ushort* Wp1   = (ushort*)walloc((size_t)2 * 16 * 64 * 8 * 2);
  ushort* Wp2   = (ushort*)walloc((size_t)8 * 16 * 64 * 8 * 2);
  ushort* Wpc   = (ushort*)walloc((size_t)3 * 8 * 16 * 64 * 8 * 2);
  int*   cnt8   = (int*)walloc((size_t)8 * N * 4);
  int*   cnt    = (int*)walloc((size_t)N * 4);
  int*   rowptr = (int*)walloc(((size_t)N + 1) * 4);
  int*   base8  = (int*)walloc((size_t)8 * N * 4);
  int*   rank   = (int*)walloc((size_t)E * 4);
  unsigned* pairs = (unsigned*)walloc((size_t)E * 4);
  float* dinv   = (float*)walloc((size_t)N * 4);
  ushort* col   = (ushort*)walloc((size_t)E * 2);
  int*   bsum   = (int*)walloc(256 * 4);
  int*   boff   = (int*)walloc(256 * 4);
  float* psum   = (float*)walloc((size_t)256 * 256 * 4);
  float* pmax   = (float*)walloc((size_t)256 * 256 * 4);
  float* s_out  = (float*)walloc(512);
  int*   flag   = (int*)walloc(512);

  // graph structure (CSR by dst, ushort col, atomic-free scatter)
  init_detect_kernel<<<(8 * N + 255) / 256, 256, 0, stream>>>(ei, flag, cnt8, 8 * N);
  count_kernel<<<(E + 255) / 256, 256, 0, stream>>>(ei, flag, cnt8, rank, pairs, E, N);
  bsum_kernel<<<B, 256, 0, stream>>>(cnt8, cnt, bsum, N);
  bscan_kernel<<<1, 256, 0, stream>>>(bsum, boff, rowptr, B, N);
  rowptr_kernel<<<B, 256, 0, stream>>>(cnt, cnt8, boff, rowptr, base8, dinv, N);
  int nScat = (E + 255) / 256;
  scatter_pack_kernel<<<nScat + 8 + 32 + 96, 256, 0, stream>>>(
      pairs, rank, base8, col, E, N, nScat, W1, Wp1, W2, Wp2, cW, Wpc);

  int gblocks = Mpad / 64;
  // encoder; GEMM1 reads f32 x directly (K=64 -> NKS=2); K=256 -> NKS=8
  gemm_mfma_kernel<2, true><<<gblocks, 256, 0, stream>>>(x, Wp1, b1, nullptr, hA, nullptr, N, 1);
  gemm_mfma_kernel<8, false><<<gblocks, 256, 0, stream>>>(hA, Wp2, b2, nullptr, hB, nullptr, N, 0);
  // GCN layers: hw' = (h @ convW) * dinv[row] -> fp8(x32); h = relu(dinv*(gather+self) + b)
  int bpc = (N + 15) / 16;  // node-blocks per chunk
  for (int l = 0; l < 3; ++l) {
    gemm_mfma_kernel<8, false><<<gblocks, 256, 0, stream>>>(
        hB, Wpc + (size_t)l * 8 * 16 * 64 * 8, nullptr, dinv, nullptr, hA8, N, 0);
    mp_chunk_kernel<<<4 * bpc, 256, 0, stream>>>(hA8, rowptr, col, dinv,
                                                 cb + (size_t)l * 256, hB, N, bpc);
  }
  // readout: pool partials; head folds the reduce
  pool_partial_kernel<<<256, 256, 0, stream>>>(hB, psum, pmax, N);
  head_kernel<<<1, 1024, 0, stream>>>(psum, pmax, Wg1, bg1, Wg2, bg2, Wd1, bd1, Wd2, bd2,
                                      out, s_out, N);
  fill_kernel<<<(E + 1023) / 1024, 256, 0, stream>>>(out + 128, s_out, E);
}

// Round 17
// 343.269 us; speedup vs baseline: 1.1912x; 1.1912x over previous
//
#include <hip/hip_runtime.h>
#include <hip/hip_bf16.h>

// GAE forward, bf16 compute path + fp8 message tensor.
//   CSR build: 8-way privatized count (saves per-edge RANK + packed (s,d) pair)
//     -> 3-phase scan (+per-copy base8) -> ATOMIC-FREE scatter (fused w/ W-pack)
//   -> 5x bf16-MFMA GEMM (K compile-time; GEMM1 converts f32 x in-register)
//   -> 3x mp gather (fp8 rows, ROW-CONTIGUOUS x16-unrolled; r15 lesson:
//      column-chunking caused 2x line amplification, full-row is line-optimal;
//      r16 lesson: tail loop double-increment dropped edges -> if-form tail)
//   -> ATOMIC-FREE pool partials -> head (1024 thr; folds partial reduce)
//   -> fill(sigmoid const)
// Lessons: r8 pool atomics ping-pong; r9 head serial-load chain; r10 scatter
// atomic serialization; r12 conv GEMM access-pattern limited; r13 dispatch gaps.
// edge_probs is constant: node_emb rows are the same broadcast vector v,
// so logit = sum(v*v) for every edge.

typedef __attribute__((ext_vector_type(8))) short bf16x8;
typedef __attribute__((ext_vector_type(4))) float f32x4;
typedef __attribute__((ext_vector_type(2))) float f32x2;

#define FP8_SCALE 32.0f
#define FP8_INV (1.0f / 32.0f)

__device__ __forceinline__ ushort f2bf(float f) {
  union { float f; unsigned u; } v; v.f = f;
  unsigned r = v.u + 0x7FFF + ((v.u >> 16) & 1);  // RNE
  return (ushort)(r >> 16);
}
__device__ __forceinline__ float bf2f(ushort b) {
  union { unsigned u; float f; } v; v.u = ((unsigned)b) << 16;
  return v.f;
}

// -------------------- CSR build --------------------

// fused: zero cnt8 + detect edge dtype (block 0 thread 0)
__global__ void init_detect_kernel(const int* __restrict__ ei, int* __restrict__ flag,
                                   int* __restrict__ cnt8, int N8) {
  int i = blockIdx.x * 256 + threadIdx.x;
  if (i < N8) cnt8[i] = 0;
  if (blockIdx.x == 0 && threadIdx.x == 0) {
    int all0 = 1;
    for (int k = 0; k < 128; ++k) {
      if (ei[2 * k + 1] != 0) { all0 = 0; break; }
    }
    flag[0] = all0;  // 1 => int64 payload (high words all zero)
  }
}

// 8-way privatized histogram; the atomic's return value IS the edge's rank
// within copy (blockIdx&7). Also emits packed (s,d) pair so scatter never
// re-reads the (possibly int64) edge list.
__global__ void count_kernel(const int* __restrict__ ei, const int* __restrict__ flag,
                             int* __restrict__ cnt8, int* __restrict__ rank,
                             unsigned* __restrict__ pairs, int E, int N) {
  int e = blockIdx.x * 256 + threadIdx.x;
  if (e >= E) return;
  int s, d;
  if (flag[0]) {
    const long long* e64 = (const long long*)ei;
    s = (int)e64[e];
    d = (int)e64[(size_t)E + e];
  } else {
    s = ei[e];
    d = ei[(size_t)E + e];
  }
  rank[e] = atomicAdd(&cnt8[(size_t)(blockIdx.x & 7) * N + d], 1);
  pairs[e] = (unsigned)s | ((unsigned)d << 16);  // s,d < 65536
}

// 3-phase multiblock exclusive scan -> rowptr[N+1], per-copy base8, dinv.
// bsum fuses the 8-copy histogram reduce (writes cnt[i] = total).

__global__ __launch_bounds__(256) void bsum_kernel(const int* __restrict__ cnt8,
                                                   int* __restrict__ cnt,
                                                   int* __restrict__ bsum, int N) {
  __shared__ int red[4];
  int t = threadIdx.x;
  int i = blockIdx.x * 256 + t;
  int v = 0;
  if (i < N) {
#pragma unroll
    for (int c = 0; c < 8; ++c) v += cnt8[(size_t)c * N + i];
    cnt[i] = v;
  }
  for (int off = 32; off > 0; off >>= 1) v += __shfl_down(v, off, 64);
  if ((t & 63) == 0) red[t >> 6] = v;
  __syncthreads();
  if (t == 0) bsum[blockIdx.x] = red[0] + red[1] + red[2] + red[3];
}

__global__ __launch_bounds__(256) void bscan_kernel(const int* __restrict__ bsum,
                                                    int* __restrict__ boff,
                                                    int* __restrict__ rowptr, int B, int N) {
  __shared__ int s[256];
  int t = threadIdx.x;
  int v = (t < B) ? bsum[t] : 0;
  s[t] = v;
  __syncthreads();
  for (int off = 1; off < 256; off <<= 1) {
    int x = s[t];
    int add = (t >= off) ? s[t - off] : 0;
    __syncthreads();
    s[t] = x + add;
    __syncthreads();
  }
  if (t < B) boff[t] = s[t] - v;  // exclusive block offset
  if (t == 255) rowptr[N] = s[255];
}

__global__ __launch_bounds__(256) void rowptr_kernel(const int* __restrict__ cnt,
                                                     const int* __restrict__ cnt8,
                                                     const int* __restrict__ boff,
                                                     int* __restrict__ rowptr,
                                                     int* __restrict__ base8,
                                                     float* __restrict__ dinv, int N) {
  __shared__ int s[256];
  int t = threadIdx.x;
  int i = blockIdx.x * 256 + t;
  int v = (i < N) ? cnt[i] : 0;
  s[t] = v;
  __syncthreads();
  for (int off = 1; off < 256; off <<= 1) {
    int x = s[t];
    int add = (t >= off) ? s[t - off] : 0;
    __syncthreads();
    s[t] = x + add;
    __syncthreads();
  }
  if (i < N) {
    int rp = boff[blockIdx.x] + s[t] - v;
    rowptr[i] = rp;
    int run = rp;
#pragma unroll
    for (int c = 0; c < 8; ++c) {            // per-copy exclusive base within the row
      base8[(size_t)c * N + i] = run;
      run += cnt8[(size_t)c * N + i];
    }
    dinv[i] = rsqrtf((float)(v + 1));  // +1 self-loop
  }
}

// ---- fused: ATOMIC-FREE scatter + weight-frag packing (independent work) ----
// Scatter: slot = base8[copy][d] + rank[e]; copy = (e>>8)&7 matches count's
// blockIdx&7 (identical 256-thr grids).
// Wp layout: [K/32][16 colblk][64 lane][8 bf16], element (ks,cb,lane,i):
//   k = ks*32 + (lane>>4)*8 + i,  n = cb*16 + (lane&15)   (MFMA B-frag order)

__global__ void scatter_pack_kernel(const unsigned* __restrict__ pairs,
                                    const int* __restrict__ rank,
                                    const int* __restrict__ base8,
                                    ushort* __restrict__ col, int E, int N, int nScat,
                                    const float* __restrict__ W1, ushort* __restrict__ Wp1,
                                    const float* __restrict__ W2, ushort* __restrict__ Wp2,
                                    const float* __restrict__ cW, ushort* __restrict__ Wpc) {
  int b = blockIdx.x;
  if (b < nScat) {
    int e = b * 256 + threadIdx.x;
    if (e >= E) return;
    unsigned p = pairs[e];
    int s = p & 0xffff;
    int d = p >> 16;
    int c = (e >> 8) & 7;
    int pos = base8[(size_t)c * N + d] + rank[e];
    col[pos] = (ushort)s;
    return;
  }
  b -= nScat;
  const float* W;
  ushort* Wp;
  int K;
  if (b < 8) { W = W1; Wp = Wp1; K = 64; }
  else if (b < 40) { W = W2; Wp = Wp2; K = 256; b -= 8; }
  else {
    int l = (b - 40) >> 5;
    W = cW + (size_t)l * 256 * 256;
    Wp = Wpc + (size_t)l * 8 * 16 * 64 * 8;
    K = 256;
    b -= 40 + l * 32;
  }
  int idx = b * 256 + threadIdx.x;
  int total = (K >> 5) * 16 * 64;
  if (idx >= total) return;
  int lane = idx & 63;
  int cb = (idx >> 6) & 15;
  int ks = idx >> 10;
  int nn = cb * 16 + (lane & 15);
  int kbase = ks * 32 + (lane >> 4) * 8;
#pragma unroll
  for (int i = 0; i < 8; ++i)
    Wp[(size_t)idx * 8 + i] = f2bf(W[(size_t)(kbase + i) * 256 + nn]);
}

// -------------------- bf16 MFMA GEMM: C[M,256] = post(A[M,K*] @ W) ------------------
// K compile-time (NKS = K/32); block = 256 thr (4 waves), tile 64x256.
// AF32: A is f32 row-major, converted to bf16 in-register (saves the cvt pass).

template <int NKS, bool AF32>
__global__ __launch_bounds__(256) void gemm_mfma_kernel(
    const void* __restrict__ Av,    // [Mpad,K] bf16 (or [M,K] f32 if AF32)
    const ushort* __restrict__ Wp,  // packed frags
    const float* __restrict__ bias, // [256] or null
    const float* __restrict__ scale,// [M] dinv or null (applied after bias/relu)
    ushort* __restrict__ C,         // [Mpad,256] bf16 (if C8 == null)
    unsigned char* __restrict__ C8, // [Mpad,256] fp8 (or null)
    int M, int relu) {
  constexpr int K = NKS * 32;
  int t = threadIdx.x;
  int lane = t & 63, wave = t >> 6;
  int l15 = lane & 15, lk = lane >> 4;
  int row0 = blockIdx.x * 64;

  f32x4 acc[4][4];
#pragma unroll
  for (int rb = 0; rb < 4; ++rb)
#pragma unroll
    for (int cb = 0; cb < 4; ++cb) acc[rb][cb] = (f32x4){0.f, 0.f, 0.f, 0.f};

  const ushort* abase[4];
  const float* afbase[4];
#pragma unroll
  for (int rb = 0; rb < 4; ++rb) {
    int arow = row0 + rb * 16 + l15;
    if (AF32) arow = min(arow, M - 1);  // clamp: keep loads in-bounds (stores guarded)
    if (AF32) afbase[rb] = (const float*)Av + (size_t)arow * K + lk * 8;
    else      abase[rb] = (const ushort*)Av + (size_t)arow * K + lk * 8;
  }
  const ushort* bbase = Wp + ((size_t)(wave * 4) * 64 + lane) * 8;

#pragma unroll
  for (int ks = 0; ks < NKS; ++ks) {
    bf16x8 a[4], b[4];
#pragma unroll
    for (int rb = 0; rb < 4; ++rb) {
      if (AF32) {
        float4 f0 = *reinterpret_cast<const float4*>(afbase[rb] + ks * 32);
        float4 f1 = *reinterpret_cast<const float4*>(afbase[rb] + ks * 32 + 4);
        bf16x8 av;
        av[0] = (short)f2bf(f0.x); av[1] = (short)f2bf(f0.y);
        av[2] = (short)f2bf(f0.z); av[3] = (short)f2bf(f0.w);
        av[4] = (short)f2bf(f1.x); av[5] = (short)f2bf(f1.y);
        av[6] = (short)f2bf(f1.z); av[7] = (short)f2bf(f1.w);
        a[rb] = av;
      } else {
        a[rb] = *reinterpret_cast<const bf16x8*>(abase[rb] + ks * 32);
      }
    }
#pragma unroll
    for (int cb = 0; cb < 4; ++cb)
      b[cb] = *reinterpret_cast<const bf16x8*>(bbase + ((size_t)ks * 16 + cb) * 64 * 8);
#pragma unroll
    for (int rb = 0; rb < 4; ++rb)
#pragma unroll
      for (int cb = 0; cb < 4; ++cb)
        acc[rb][cb] = __builtin_amdgcn_mfma_f32_16x16x32_bf16(a[rb], b[cb], acc[rb][cb], 0, 0, 0);
  }

  float bv[4];
#pragma unroll
  for (int cb = 0; cb < 4; ++cb)
    bv[cb] = bias ? bias[wave * 64 + cb * 16 + l15] : 0.f;

#pragma unroll
  for (int rb = 0; rb < 4; ++rb) {
    int rbase = row0 + rb * 16 + lk * 4;
#pragma unroll
    for (int r = 0; r < 4; ++r) {
      int row = rbase + r;
      if (row >= M) continue;
      float sc = scale ? scale[row] : 1.f;
#pragma unroll
      for (int cb = 0; cb < 4; ++cb) {
        float v = acc[rb][cb][r] + bv[cb];
        if (relu) v = fmaxf(v, 0.f);
        v *= sc;
        int colIdx = wave * 64 + cb * 16 + l15;
        if (C8) {
          float vq = fminf(fmaxf(v * FP8_SCALE, -448.f), 448.f);
          unsigned p = __builtin_amdgcn_cvt_pk_fp8_f32(vq, vq, 0, false);
          C8[(size_t)row * 256 + colIdx] = (unsigned char)(p & 0xff);
        } else {
          C[(size_t)row * 256 + colIdx] = f2bf(v);
        }
      }
    }
  }
}

// -------- message passing: h[n] = relu(dinv[n]*(sum_{s in in(n)} hw'[s] + hw'[n]) + b) ----
// hw' rows are fp8 e4m3 of (hw * dinv[src] * FP8_SCALE); dn folds dinv[n]/FP8_SCALE.
// Row-contiguous gathers; x16 unroll, one-shot x4 tail (if-form! r16 bug), x1 tail.

__global__ __launch_bounds__(64) void mp_kernel(const unsigned char* __restrict__ hw8,
                                                const int* __restrict__ rowptr,
                                                const ushort* __restrict__ col,
                                                const float* __restrict__ dinv,
                                                const float* __restrict__ bias,
                                                ushort* __restrict__ hout) {
  int n = blockIdx.x;
  int t = threadIdx.x;  // 64 lanes x 4 fp8 = 256 cols
  const unsigned* hw32 = reinterpret_cast<const unsigned*>(hw8);
  unsigned ws = hw32[(size_t)n * 64 + t];  // self
  f32x2 lo = __builtin_amdgcn_cvt_pk_f32_fp8(ws, false);
  f32x2 hi = __builtin_amdgcn_cvt_pk_f32_fp8(ws, true);
  float ax = lo[0], ay = lo[1], az = hi[0], aw = hi[1];
  int beg = rowptr[n], end = rowptr[n + 1];
  int j = beg;
  for (; j + 16 <= end; j += 16) {
    int ss[16];
    unsigned ww[16];
#pragma unroll
    for (int q = 0; q < 16; ++q) ss[q] = col[j + q];
#pragma unroll
    for (int q = 0; q < 16; ++q) ww[q] = hw32[(size_t)ss[q] * 64 + t];
#pragma unroll
    for (int q = 0; q < 16; ++q) {
      f32x2 lq = __builtin_amdgcn_cvt_pk_f32_fp8(ww[q], false);
      f32x2 hq = __builtin_amdgcn_cvt_pk_f32_fp8(ww[q], true);
      ax += lq[0]; ay += lq[1]; az += hq[0]; aw += hq[1];
    }
  }
  if (j + 8 <= end) {  // one-shot x8 tail
    int ss[8];
    unsigned ww[8];
#pragma unroll
    for (int q = 0; q < 8; ++q) ss[q] = col[j + q];
#pragma unroll
    for (int q = 0; q < 8; ++q) ww[q] = hw32[(size_t)ss[q] * 64 + t];
#pragma unroll
    for (int q = 0; q < 8; ++q) {
      f32x2 lq = __builtin_amdgcn_cvt_pk_f32_fp8(ww[q], false);
      f32x2 hq = __builtin_amdgcn_cvt_pk_f32_fp8(ww[q], true);
      ax += lq[0]; ay += lq[1]; az += hq[0]; aw += hq[1];
    }
    j += 8;
  }
  if (j + 4 <= end) {  // one-shot x4 tail
    int s0 = col[j], s1 = col[j + 1], s2 = col[j + 2], s3 = col[j + 3];
    unsigned w0 = hw32[(size_t)s0 * 64 + t];
    unsigned w1 = hw32[(size_t)s1 * 64 + t];
    unsigned w2 = hw32[(size_t)s2 * 64 + t];
    unsigned w3 = hw32[(size_t)s3 * 64 + t];
    f32x2 l0 = __builtin_amdgcn_cvt_pk_f32_fp8(w0, false);
    f32x2 h0 = __builtin_amdgcn_cvt_pk_f32_fp8(w0, true);
    f32x2 l1 = __builtin_amdgcn_cvt_pk_f32_fp8(w1, false);
    f32x2 h1 = __builtin_amdgcn_cvt_pk_f32_fp8(w1, true);
    f32x2 l2 = __builtin_amdgcn_cvt_pk_f32_fp8(w2, false);
    f32x2 h2 = __builtin_amdgcn_cvt_pk_f32_fp8(w2, true);
    f32x2 l3 = __builtin_amdgcn_cvt_pk_f32_fp8(w3, false);
    f32x2 h3 = __builtin_amdgcn_cvt_pk_f32_fp8(w3, true);
    ax += (l0[0] + l1[0]) + (l2[0] + l3[0]);
    ay += (l0[1] + l1[1]) + (l2[1] + l3[1]);
    az += (h0[0] + h1[0]) + (h2[0] + h3[0]);
    aw += (h0[1] + h1[1]) + (h2[1] + h3[1]);
    j += 4;
  }
  for (; j < end; ++j) {
    int s = col[j];
    unsigned wv = hw32[(size_t)s * 64 + t];
    f32x2 l2 = __builtin_amdgcn_cvt_pk_f32_fp8(wv, false);
    f32x2 h2 = __builtin_amdgcn_cvt_pk_f32_fp8(wv, true);
    ax += l2[0]; ay += l2[1]; az += h2[0]; aw += h2[1];
  }
  float dn = dinv[n] * FP8_INV;
  float4 bv = *reinterpret_cast<const float4*>(bias + t * 4);
  ushort4 o;
  o.x = f2bf(fmaxf(fmaf(dn, ax, bv.x), 0.f));
  o.y = f2bf(fmaxf(fmaf(dn, ay, bv.y), 0.f));
  o.z = f2bf(fmaxf(fmaf(dn, az, bv.z), 0.f));
  o.w = f2bf(fmaxf(fmaf(dn, aw, bv.w), 0.f));
  *reinterpret_cast<ushort4*>(hout + (size_t)n * 256 + t * 4) = o;
}

// ---------- pooling, ATOMIC-FREE: per-block partials (reduced inside head) ----------

__global__ __launch_bounds__(256) void pool_partial_kernel(const ushort* __restrict__ h,
                                                           float* __restrict__ psum,
                                                           float* __restrict__ pmax, int N) {
  __shared__ float ssum[4][256];
  __shared__ float smax[4][256];
  int t = threadIdx.x;
  int w = t >> 6, l = t & 63;
  int gw = blockIdx.x * 4 + w;  // 0..1023
  float s0 = 0.f, s1 = 0.f, s2 = 0.f, s3 = 0.f;
  float m0 = 0.f, m1 = 0.f, m2 = 0.f, m3 = 0.f;  // h >= 0 after relu
  const ushort4 z = {0, 0, 0, 0};
  for (int r = gw; r < N; r += 8192) {
    ushort4 v[8];
#pragma unroll
    for (int j = 0; j < 8; ++j) {
      int rj = r + j * 1024;
      v[j] = (rj < N) ? *reinterpret_cast<const ushort4*>(h + (size_t)rj * 256 + l * 4) : z;
    }
#pragma unroll
    for (int j = 0; j < 8; ++j) {
      float a0 = bf2f(v[j].x), a1 = bf2f(v[j].y), a2 = bf2f(v[j].z), a3 = bf2f(v[j].w);
      s0 += a0; s1 += a1; s2 += a2; s3 += a3;
      m0 = fmaxf(m0, a0); m1 = fmaxf(m1, a1); m2 = fmaxf(m2, a2); m3 = fmaxf(m3, a3);
    }
  }
  ssum[w][l * 4] = s0; ssum[w][l * 4 + 1] = s1; ssum[w][l * 4 + 2] = s2; ssum[w][l * 4 + 3] = s3;
  smax[w][l * 4] = m0; smax[w][l * 4 + 1] = m1; smax[w][l * 4 + 2] = m2; smax[w][l * 4 + 3] = m3;
  __syncthreads();
  float s = ssum[0][t] + ssum[1][t] + ssum[2][t] + ssum[3][t];
  float m = fmaxf(fmaxf(smax[0][t], smax[1][t]), fmaxf(smax[2][t], smax[3][t]));
  psum[(size_t)blockIdx.x * 256 + t] = s;
  pmax[(size_t)blockIdx.x * 256 + t] = m;
}

// ------- head: folds pool partial-reduce + 4 tiny GEMM layers + logit -------

__global__ __launch_bounds__(1024) void head_kernel(const float* __restrict__ psum,
                                                    const float* __restrict__ pmax,
                                                    const float* __restrict__ Wg1, const float* __restrict__ bg1,
                                                    const float* __restrict__ Wg2, const float* __restrict__ bg2,
                                                    const float* __restrict__ Wd1, const float* __restrict__ bd1,
                                                    const float* __restrict__ Wd2, const float* __restrict__ bd2,
                                                    float* __restrict__ out_ge, float* __restrict__ s_out, int N) {
  __shared__ float gr[512];
  __shared__ float part[4][256];  // also reused flat as [8][128]
  __shared__ float t1[256];
  __shared__ float ge[128];
  __shared__ float t2[256];
  __shared__ float vv[256];
  __shared__ float red[4];
  int t = threadIdx.x;
  float* pf = &part[0][0];

  // fold 256 pool partials: sum
  {
    int kg = t >> 8, c = t & 255;
    const float* base = psum + (size_t)(kg * 64) * 256 + c;
    float a = 0.f;
#pragma unroll
    for (int i = 0; i < 64; i += 4)
      a += (base[(size_t)i * 256] + base[(size_t)(i + 1) * 256]) +
           (base[(size_t)(i + 2) * 256] + base[(size_t)(i + 3) * 256]);
    part[kg][c] = a;
  }
  __syncthreads();
  if (t < 256) gr[t] = (part[0][t] + part[1][t] + part[2][t] + part[3][t]) / (float)N;
  __syncthreads();
  // fold max
  {
    int kg = t >> 8, c = t & 255;
    const float* base = pmax + (size_t)(kg * 64) * 256 + c;
    float m = 0.f;
#pragma unroll
    for (int i = 0; i < 64; i += 4)
      m = fmaxf(m, fmaxf(fmaxf(base[(size_t)i * 256], base[(size_t)(i + 1) * 256]),
                         fmaxf(base[(size_t)(i + 2) * 256], base[(size_t)(i + 3) * 256])));
    part[kg][c] = m;
  }
  __syncthreads();
  if (t < 256)
    gr[256 + t] = fmaxf(fmaxf(part[0][t], part[1][t]), fmaxf(part[2][t], part[3][t]));
  __syncthreads();

  // layer 1: t1 = relu(gr[512] @ Wg1[512,256] + bg1); kg in 0..3 takes 128 k
  {
    int kg = t >> 8, c = t & 255, k0 = kg * 128;
    float a0 = 0, a1 = 0, a2 = 0, a3 = 0, a4 = 0, a5 = 0, a6 = 0, a7 = 0;
    for (int k = k0; k < k0 + 128; k += 8) {
      a0 = fmaf(gr[k + 0], Wg1[(size_t)(k + 0) * 256 + c], a0);
      a1 = fmaf(gr[k + 1], Wg1[(size_t)(k + 1) * 256 + c], a1);
      a2 = fmaf(gr[k + 2], Wg1[(size_t)(k + 2) * 256 + c], a2);
      a3 = fmaf(gr[k + 3], Wg1[(size_t)(k + 3) * 256 + c], a3);
      a4 = fmaf(gr[k + 4], Wg1[(size_t)(k + 4) * 256 + c], a4);
      a5 = fmaf(gr[k + 5], Wg1[(size_t)(k + 5) * 256 + c], a5);
      a6 = fmaf(gr[k + 6], Wg1[(size_t)(k + 6) * 256 + c], a6);
      a7 = fmaf(gr[k + 7], Wg1[(size_t)(k + 7) * 256 + c], a7);
    }
    part[kg][c] = ((a0 + a1) + (a2 + a3)) + ((a4 + a5) + (a6 + a7));
  }
  __syncthreads();
  if (t < 256) t1[t] = fmaxf(part[0][t] + part[1][t] + part[2][t] + part[3][t] + bg1[t], 0.f);
  __syncthreads();

  // layer 2: ge = t1[256] @ Wg2[256,128] + bg2; kg in 0..7 takes 32 k
  {
    int kg = t >> 7, c = t & 127, k0 = kg * 32;
    float a0 = 0, a1 = 0, a2 = 0, a3 = 0;
    for (int k = k0; k < k0 + 32; k += 4) {
      a0 = fmaf(t1[k + 0], Wg2[(size_t)(k + 0) * 128 + c], a0);
      a1 = fmaf(t1[k + 1], Wg2[(size_t)(k + 1) * 128 + c], a1);
      a2 = fmaf(t1[k + 2], Wg2[(size_t)(k + 2) * 128 + c], a2);
      a3 = fmaf(t1[k + 3], Wg2[(size_t)(k + 3) * 128 + c], a3);
    }
    pf[kg * 128 + c] = (a0 + a1) + (a2 + a3);
  }
  __syncthreads();
  if (t < 128) {
    float s = bg2[t];
#pragma unroll
    for (int g = 0; g < 8; ++g) s += pf[g * 128 + t];
    ge[t] = s;
    out_ge[t] = s;  // output 0: graph_embedding
  }
  __syncthreads();

  // layer 3: t2 = relu(ge[128] @ Wd1[128,256] + bd1); kg in 0..3 takes 32 k
  {
    int kg = t >> 8, c = t & 255, k0 = kg * 32;
    float a0 = 0, a1 = 0, a2 = 0, a3 = 0;
    for (int k = k0; k < k0 + 32; k += 4) {
      a0 = fmaf(ge[k + 0], Wd1[(size_t)(k + 0) * 256 + c], a0);
      a1 = fmaf(ge[k + 1], Wd1[(size_t)(k + 1) * 256 + c], a1);
      a2 = fmaf(ge[k + 2], Wd1[(size_t)(k + 2) * 256 + c], a2);
      a3 = fmaf(ge[k + 3], Wd1[(size_t)(k + 3) * 256 + c], a3);
    }
    part[kg][c] = (a0 + a1) + (a2 + a3);
  }
  __syncthreads();
  if (t < 256) t2[t] = fmaxf(part[0][t] + part[1][t] + part[2][t] + part[3][t] + bd1[t], 0.f);
  __syncthreads();

  // layer 4: vv = t2[256] @ Wd2[256,256] + bd2; kg in 0..3 takes 64 k
  {
    int kg = t >> 8, c = t & 255, k0 = kg * 64;
    float a0 = 0, a1 = 0, a2 = 0, a3 = 0, a4 = 0, a5 = 0, a6 = 0, a7 = 0;
    for (int k = k0; k < k0 + 64; k += 8) {
      a0 = fmaf(t2[k + 0], Wd2[(size_t)(k + 0) * 256 + c], a0);
      a1 = fmaf(t2[k + 1], Wd2[(size_t)(k + 1) * 256 + c], a1);
      a2 = fmaf(t2[k + 2], Wd2[(size_t)(k + 2) * 256 + c], a2);
      a3 = fmaf(t2[k + 3], Wd2[(size_t)(k + 3) * 256 + c], a3);
      a4 = fmaf(t2[k + 4], Wd2[(size_t)(k + 4) * 256 + c], a4);
      a5 = fmaf(t2[k + 5], Wd2[(size_t)(k + 5) * 256 + c], a5);
      a6 = fmaf(t2[k + 6], Wd2[(size_t)(k + 6) * 256 + c], a6);
      a7 = fmaf(t2[k + 7], Wd2[(size_t)(k + 7) * 256 + c], a7);
    }
    part[kg][c] = ((a0 + a1) + (a2 + a3)) + ((a4 + a5) + (a6 + a7));
  }
  __syncthreads();
  if (t < 256) vv[t] = part[0][t] + part[1][t] + part[2][t] + part[3][t] + bd2[t];
  __syncthreads();

  // logit = sum(vv^2); sigmoid
  if (t < 256) {
    float p = vv[t] * vv[t];
    for (int off = 32; off > 0; off >>= 1) p += __shfl_down(p, off, 64);
    if ((t & 63) == 0) red[t >> 6] = p;
  }
  __syncthreads();
  if (t == 0) {
    float ssq = red[0] + red[1] + red[2] + red[3];
    s_out[0] = 1.f / (1.f + expf(-ssq));
  }
}

__global__ void fill_kernel(float* __restrict__ out, const float* __restrict__ s_out, int E) {
  int i = (blockIdx.x * 256 + threadIdx.x) * 4;
  if (i + 4 <= E) {
    float s = s_out[0];
    *reinterpret_cast<float4*>(out + i) = make_float4(s, s, s, s);
  } else {
    for (int j = i; j < E; ++j) out[j] = s_out[0];
  }
}

// -------------------- launch --------------------

extern "C" void kernel_launch(void* const* d_in, const int* in_sizes, int n_in,
                              void* d_out, int out_size, void* d_ws, size_t ws_size,
                              hipStream_t stream) {
  const float* x   = (const float*)d_in[0];
  const int*   ei  = (const int*)d_in[1];
  const float* W1  = (const float*)d_in[2];
  const float* b1  = (const float*)d_in[3];
  const float* W2  = (const float*)d_in[4];
  const float* b2  = (const float*)d_in[5];
  const float* cW  = (const float*)d_in[6];
  const float* cb  = (const float*)d_in[7];
  const float* Wg1 = (const float*)d_in[8];
  const float* bg1 = (const float*)d_in[9];
  const float* Wg2 = (const float*)d_in[10];
  const float* bg2 = (const float*)d_in[11];
  const float* Wd1 = (const float*)d_in[12];
  const float* bd1 = (const float*)d_in[13];
  const float* Wd2 = (const float*)d_in[14];
  const float* bd2 = (const float*)d_in[15];
  float* out = (float*)d_out;

  int N = in_sizes[0] / 64;  // 50000
  int E = in_sizes[1] / 2;   // 800000
  int Mpad = (N + 63) & ~63; // 50048
  int B = (N + 255) / 256;   // scan blocks (196)

  size_t off = 0;
  auto walloc = [&](size_t bytes) -> void* {
    void* p = (char*)d_ws + off;
    off += (bytes + 511) & ~(size_t)511;
    return p;
  };
  ushort* hA    = (ushort*)walloc((size_t)Mpad * 256 * 2);
  ushort* hB    = (ushort*)walloc((size_t)Mpad * 256 * 2);
  unsigned char* hA8 = (unsigned char*)walloc((size_t)Mpad * 256);
  ushort* Wp1   = (ushort*)walloc((size_t)2 * 16 * 64 * 8 * 2);
  ushort* Wp2   = (ushort*)walloc((size_t)8 * 16 * 64 * 8 * 2);
  ushort* Wpc   = (ushort*)walloc((size_t)3 * 8 * 16 * 64 * 8 * 2);
  int*   cnt8   = (int*)walloc((size_t)8 * N * 4);
  int*   cnt    = (int*)walloc((size_t)N * 4);
  int*   rowptr = (int*)walloc(((size_t)N + 1) * 4);
  int*   base8  = (int*)walloc((size_t)8 * N * 4);
  int*   rank   = (int*)walloc((size_t)E * 4);
  unsigned* pairs = (unsigned*)walloc((size_t)E * 4);
  float* dinv   = (float*)walloc((size_t)N * 4);
  ushort* col   = (ushort*)walloc((size_t)E * 2);
  int*   bsum   = (int*)walloc(256 * 4);
  int*   boff   = (int*)walloc(256 * 4);
  float* psum   = (float*)walloc((size_t)256 * 256 * 4);
  float* pmax   = (float*)walloc((size_t)256 * 256 * 4);
  float* s_out  = (float*)walloc(512);
  int*   flag   = (int*)walloc(512);

  // graph structure (CSR by dst, ushort col, atomic-free scatter)
  init_detect_kernel<<<(8 * N + 255) / 256, 256, 0, stream>>>(ei, flag, cnt8, 8 * N);
  count_kernel<<<(E + 255) / 256, 256, 0, stream>>>(ei, flag, cnt8, rank, pairs, E, N);
  bsum_kernel<<<B, 256, 0, stream>>>(cnt8, cnt, bsum, N);
  bscan_kernel<<<1, 256, 0, stream>>>(bsum, boff, rowptr, B, N);
  rowptr_kernel<<<B, 256, 0, stream>>>(cnt, cnt8, boff, rowptr, base8, dinv, N);
  int nScat = (E + 255) / 256;
  scatter_pack_kernel<<<nScat + 8 + 32 + 96, 256, 0, stream>>>(
      pairs, rank, base8, col, E, N, nScat, W1, Wp1, W2, Wp2, cW, Wpc);

  int gblocks = Mpad / 64;
  // encoder; GEMM1 reads f32 x directly (K=64 -> NKS=2); K=256 -> NKS=8
  gemm_mfma_kernel<2, true><<<gblocks, 256, 0, stream>>>(x, Wp1, b1, nullptr, hA, nullptr, N, 1);
  gemm_mfma_kernel<8, false><<<gblocks, 256, 0, stream>>>(hA, Wp2, b2, nullptr, hB, nullptr, N, 0);
  // GCN layers: hw' = (h @ convW) * dinv[row] -> fp8(x32); h = relu(dinv*(gather+self) + b)
  for (int l = 0; l < 3; ++l) {
    gemm_mfma_kernel<8, false><<<gblocks, 256, 0, stream>>>(
        hB, Wpc + (size_t)l * 8 * 16 * 64 * 8, nullptr, dinv, nullptr, hA8, N, 0);
    mp_kernel<<<N, 64, 0, stream>>>(hA8, rowptr, col, dinv, cb + (size_t)l * 256, hB);
  }
  // readout: pool partials; head folds the reduce
  pool_partial_kernel<<<256, 256, 0, stream>>>(hB, psum, pmax, N);
  head_kernel<<<1, 1024, 0, stream>>>(psum, pmax, Wg1, bg1, Wg2, bg2, Wd1, bd1, Wd2, bd2,
                                      out, s_out, N);
  fill_kernel<<<(E + 1023) / 1024, 256, 0, stream>>>(out + 128, s_out, E);
}